// Round 1
// baseline (1362.796 us; speedup 1.0000x reference)
//
#include <hip/hip_runtime.h>
#include <cstdint>
#include <cstddef>

// ---------------------------------------------------------------------------
// Fused GQA attention block for MI355X (gfx950).
// B=4 T=1024 D=4096 N=32 Kh=8 G=4 H=128, rotary=80, theta=1e6, eps=1e-6.
// Pipeline: [transpose+cvt weights/x -> bf16] -> GEMM(qkv) -> norm/rope/gate
//           -> flash attention (causal, online softmax) -> GEMM(out proj).
// All matmuls use v_mfma_f32_16x16x32_bf16 with the guide-verified layouts:
//   A-frag: A[m=lane&15][k=(lane>>4)*8+j]   (8 contiguous k per lane)
//   B-frag: B[k=(lane>>4)*8+j][n=lane&15]   (from B^T, 8 contiguous k)
//   C/D   : row=(lane>>4)*4+r, col=lane&15
// Workspace requirement: ~304 MiB.
// ---------------------------------------------------------------------------

typedef __attribute__((ext_vector_type(8))) short short8;
typedef __attribute__((ext_vector_type(4))) float float4v;

__device__ __forceinline__ unsigned short f2bf(float f) {
  unsigned u = __builtin_bit_cast(unsigned, f);
  u += 0x7fffu + ((u >> 16) & 1u);            // RNE
  return (unsigned short)(u >> 16);
}
__device__ __forceinline__ float bf2f(unsigned short h) {
  unsigned u = ((unsigned)h) << 16;
  return __builtin_bit_cast(float, u);
}

// async global->LDS, 16B per lane. LDS dest must be wave-uniform base + lane*16.
__device__ __forceinline__ void gload_lds16(const void* g, void* l) {
  typedef const __attribute__((address_space(1))) void as1_cv;
  typedef __attribute__((address_space(3))) void as3_v;
  __builtin_amdgcn_global_load_lds((as1_cv*)g, (as3_v*)l, 16, 0, 0);
}

// ---------------------------------------------------------------------------
// Transpose + f32->bf16 convert: dst[c][r] = bf16(src[r][c]); src is (R, C).
// grid (C/32, R/32), block (32, 8).
// ---------------------------------------------------------------------------
__global__ __launch_bounds__(256) void transpose_cvt(
    const float* __restrict__ src, unsigned short* __restrict__ dst,
    int R, int C) {
  __shared__ float tile[32][33];
  const int c0 = blockIdx.x * 32, r0 = blockIdx.y * 32;
  for (int i = threadIdx.y; i < 32; i += 8)
    tile[i][threadIdx.x] = src[(size_t)(r0 + i) * C + c0 + threadIdx.x];
  __syncthreads();
  for (int i = threadIdx.y; i < 32; i += 8)
    dst[(size_t)(c0 + i) * R + r0 + threadIdx.x] = f2bf(tile[threadIdx.x][i]);
}

// f32 -> bf16 elementwise (x), vectorized 4/thread.
__global__ __launch_bounds__(256) void cvt_f32_bf16(
    const float* __restrict__ src, unsigned short* __restrict__ dst, int n4) {
  int i = blockIdx.x * blockDim.x + threadIdx.x;
  if (i >= n4) return;
  float4 f = ((const float4*)src)[i];
  ushort4 o;
  o.x = f2bf(f.x); o.y = f2bf(f.y); o.z = f2bf(f.z); o.w = f2bf(f.w);
  ((ushort4*)dst)[i] = o;
}

// ---------------------------------------------------------------------------
// GEMM: C(M,N) = A(M,Kd) * BT(N,Kd)^T, all bf16 in, f32 acc.
// 128x128 block tile, BK=64, 4 waves in 2x2, 4x4 MFMA tiles per wave.
// ---------------------------------------------------------------------------
template <bool BF16OUT>
__global__ __launch_bounds__(256) void gemm_bt(
    const unsigned short* __restrict__ A, const unsigned short* __restrict__ BT,
    void* __restrict__ Cv, int M, int N, int Kd) {
  constexpr int BK = 64;
  __shared__ unsigned short As[128 * BK];
  __shared__ unsigned short Bs[128 * BK];

  const int tid = threadIdx.x;
  const int lane = tid & 63;
  const int wv = tid >> 6;
  const int wr = wv >> 1, wc = wv & 1;
  const int m0 = blockIdx.y * 128, n0 = blockIdx.x * 128;
  const int ml = lane & 15, q = lane >> 4;

  // staging: chunk li = it*256 + tid; row = li>>3 = (tid>>3)+32*it; col8 = (tid&7)*8
  const int r0 = tid >> 3;
  const int c0 = (tid & 7) * 8;
  const unsigned short* gA = A + (size_t)(m0 + r0) * Kd + c0;
  const unsigned short* gB = BT + (size_t)(n0 + r0) * Kd + c0;
  unsigned short* lA = &As[r0 * BK + c0];
  unsigned short* lB = &Bs[r0 * BK + c0];

  float4v acc[4][4];
#pragma unroll
  for (int i = 0; i < 4; ++i)
#pragma unroll
    for (int j = 0; j < 4; ++j) acc[i][j] = (float4v)0.0f;

  for (int k0 = 0; k0 < Kd; k0 += BK) {
#pragma unroll
    for (int it = 0; it < 4; ++it) {
      gload_lds16(gA + (size_t)it * 32 * Kd + k0, lA + it * 32 * BK);
      gload_lds16(gB + (size_t)it * 32 * Kd + k0, lB + it * 32 * BK);
    }
    __syncthreads();  // compiler emits vmcnt(0) drain before barrier
#pragma unroll
    for (int ks = 0; ks < 2; ++ks) {
      short8 af[4], bfr[4];
#pragma unroll
      for (int i = 0; i < 4; ++i)
        af[i] = *(const short8*)&As[(wr * 64 + i * 16 + ml) * BK + ks * 32 + q * 8];
#pragma unroll
      for (int j = 0; j < 4; ++j)
        bfr[j] = *(const short8*)&Bs[(wc * 64 + j * 16 + ml) * BK + ks * 32 + q * 8];
#pragma unroll
      for (int i = 0; i < 4; ++i)
#pragma unroll
        for (int j = 0; j < 4; ++j)
          acc[i][j] = __builtin_amdgcn_mfma_f32_16x16x32_bf16(af[i], bfr[j], acc[i][j], 0, 0, 0);
    }
    __syncthreads();
  }

#pragma unroll
  for (int i = 0; i < 4; ++i) {
#pragma unroll
    for (int j = 0; j < 4; ++j) {
      const int grow = m0 + wr * 64 + i * 16 + q * 4;
      const int gcol = n0 + wc * 64 + j * 16 + ml;
#pragma unroll
      for (int r = 0; r < 4; ++r) {
        size_t idx = (size_t)(grow + r) * N + gcol;
        if constexpr (BF16OUT)
          ((unsigned short*)Cv)[idx] = f2bf(acc[i][j][r]);
        else
          ((float*)Cv)[idx] = acc[i][j][r];
      }
    }
  }
}

// ---------------------------------------------------------------------------
// Postprocess qkv_raw (M=4096 rows, 10240 cols bf16):
//   cols [n*256, n*256+128)   : q head n      -> rmsnorm, rope, q_rot
//   cols [n*256+128, n*256+256): gate head n  -> sigmoid -> sg
//   cols [8192 + kh*128 ...)  : k head        -> rmsnorm, rope, k_rot
//   cols [9216 + kh*128 ...)  : v head        -> vt (transposed (b,kh,h,s))
// One wave per (row m, slot hs in 0..47). block=256 (4 waves).
// ---------------------------------------------------------------------------
__global__ __launch_bounds__(256) void postproc_kernel(
    const unsigned short* __restrict__ qkv, const int* __restrict__ positions,
    const float* __restrict__ qnw, const float* __restrict__ knw,
    unsigned short* __restrict__ q_rot, unsigned short* __restrict__ sgb,
    unsigned short* __restrict__ k_rot, unsigned short* __restrict__ vtb) {
  const int wave = threadIdx.x >> 6, lane = threadIdx.x & 63;
  const int gslot = blockIdx.x * 4 + wave;
  const int m = gslot / 48, hs = gslot % 48;
  const int b = m >> 10, t = m & 1023;

  const unsigned short* base;
  if (hs < 32)       base = qkv + (size_t)m * 10240 + hs * 256;
  else if (hs < 40)  base = qkv + (size_t)m * 10240 + 8192 + (hs - 32) * 128;
  else               base = qkv + (size_t)m * 10240 + 9216 + (hs - 40) * 128;

  float v1 = bf2f(base[lane]);        // h = lane
  float v2 = bf2f(base[64 + lane]);   // h = lane + 64

  if (hs >= 40) {  // V: transpose-store only
    const int kh = hs - 40;
    size_t vb = ((size_t)(b * 8 + kh) * 128) * 1024 + t;
    vtb[vb + (size_t)lane * 1024] = f2bf(v1);
    vtb[vb + (size_t)(lane + 64) * 1024] = f2bf(v2);
    return;
  }

  // RMS norm over 128 (weight (1+w) applied BEFORE rope; rope mixes channels)
  float ss = v1 * v1 + v2 * v2;
  for (int off = 32; off > 0; off >>= 1) ss += __shfl_xor(ss, off);
  const float r = rsqrtf(ss * (1.0f / 128.0f) + 1e-6f);
  const float* nw = (hs < 32) ? qnw : knw;
  v1 *= r * (1.0f + nw[lane]);
  v2 *= r * (1.0f + nw[64 + lane]);

  // RoPE on dims 0..79: pair (i, i+40), i in 0..39. ln(1e6)/40 = 0.34538776...
  const float pos = (float)positions[m];
  const int i1 = (lane < 40) ? lane : lane - 40;
  const float ang1 = pos * expf(-0.3453877639491068f * (float)i1);
  const float s1 = sinf(ang1), c1 = cosf(ang1);
  const float ang2 = pos * expf(-0.3453877639491068f * (float)(lane + 24));
  const float s2 = sinf(ang2), c2 = cosf(ang2);

  const float shA1 = __shfl(v1, (lane + 40) & 63);
  const float shA2 = __shfl(v2, (lane + 40) & 63);
  const float shX = __shfl(v1, (lane + 24) & 63);
  const float pA = (lane < 24) ? shA1 : shA2;  // x[lane+40]
  const float o1 = (lane < 40) ? (v1 * c1 - pA * s1) : (v1 * c1 + shX * s1);
  const float o2 = (lane < 16) ? (v2 * c2 + shX * s2) : v2;

  if (hs < 32) {
    size_t qb = ((size_t)m * 32 + hs) * 128;
    q_rot[qb + lane] = f2bf(o1);
    q_rot[qb + 64 + lane] = f2bf(o2);
    float g1 = bf2f(base[128 + lane]), g2 = bf2f(base[192 + lane]);
    sgb[qb + lane] = f2bf(1.0f / (1.0f + expf(-g1)));
    sgb[qb + 64 + lane] = f2bf(1.0f / (1.0f + expf(-g2)));
  } else {
    const int kh = hs - 32;
    size_t kb = ((size_t)(b * 8 + kh) * 1024 + t) * 128;
    k_rot[kb + lane] = f2bf(o1);
    k_rot[kb + 64 + lane] = f2bf(o2);
  }
}

// ---------------------------------------------------------------------------
// Flash attention. Block = (b, n, 64-row Q tile). 4 waves x 16 q-rows.
// S-tiles of 64 keys; online softmax; P via LDS (C-layout -> A-layout).
// LDS: Ks 16KB + Vts 16KB + Ps 8KB = 40KB.
// ---------------------------------------------------------------------------
__global__ __launch_bounds__(256) void attn_kernel(
    const unsigned short* __restrict__ q_rot, const unsigned short* __restrict__ k_rot,
    const unsigned short* __restrict__ vt, const unsigned short* __restrict__ sgate,
    unsigned short* __restrict__ attn_out) {
  __shared__ unsigned short Ks[64 * 128];
  __shared__ unsigned short Vts[128 * 64];
  __shared__ unsigned short Ps[64 * 64];

  const int tid = threadIdx.x;
  const int lane = tid & 63, w = tid >> 6;
  const int qt = blockIdx.x & 15;
  const int n = (blockIdx.x >> 4) & 31;
  const int b = blockIdx.x >> 9;
  const int kh = n >> 2;
  const int t0 = qt * 64;
  const int ml = lane & 15, q = lane >> 4;
  const float SCALE = 0.08838834764831845f;  // H^-0.5

  // Q a-frags: fixed for whole block -> registers, straight from global.
  short8 aq[4];
  {
    const unsigned short* qp =
        q_rot + (((size_t)(b * 1024 + t0 + w * 16 + ml)) * 32 + n) * 128 + q * 8;
#pragma unroll
    for (int ks = 0; ks < 4; ++ks) aq[ks] = *(const short8*)(qp + ks * 32);
  }

  float4v O[8];
#pragma unroll
  for (int i = 0; i < 8; ++i) O[i] = (float4v)0.0f;
  float mrow[4] = {-3e38f, -3e38f, -3e38f, -3e38f};
  float lrow[4] = {0.f, 0.f, 0.f, 0.f};

  const unsigned short* kbase = k_rot + (size_t)(b * 8 + kh) * 1024 * 128;
  const unsigned short* vbase = vt + (size_t)(b * 8 + kh) * 128 * 1024;
  const int rK = tid >> 4, cK = tid & 15;  // K stage: 64 rows x 16 chunks
  const int rV = tid >> 3, cV = tid & 7;   // V stage: 128 rows x 8 chunks

  for (int si = 0; si <= qt; ++si) {
    const int s0 = si * 64;
#pragma unroll
    for (int it = 0; it < 4; ++it) {
      const int li = it * 256 + tid;
      gload_lds16(kbase + (size_t)(s0 + rK + it * 16) * 128 + cK * 8, &Ks[li * 8]);
      gload_lds16(vbase + (size_t)(rV + it * 32) * 1024 + s0 + cV * 8, &Vts[li * 8]);
    }
    __syncthreads();

    // S = Q K^T  (acc over h = 4 ksteps)
    float4v Sv[4];
#pragma unroll
    for (int j = 0; j < 4; ++j) Sv[j] = (float4v)0.0f;
#pragma unroll
    for (int ks = 0; ks < 4; ++ks) {
#pragma unroll
      for (int j = 0; j < 4; ++j) {
        short8 bk = *(const short8*)&Ks[(j * 16 + ml) * 128 + ks * 32 + q * 8];
        Sv[j] = __builtin_amdgcn_mfma_f32_16x16x32_bf16(aq[ks], bk, Sv[j], 0, 0, 0);
      }
    }

    // scale + causal mask + online softmax (rows owned: t = t0+w*16+q*4+rr)
    float P[4][4];
#pragma unroll
    for (int rr = 0; rr < 4; ++rr) {
      const int tg = t0 + w * 16 + q * 4 + rr;
      float vmax = -3e38f;
#pragma unroll
      for (int j = 0; j < 4; ++j) {
        const int sj = s0 + j * 16 + ml;
        float v = Sv[j][rr] * SCALE;
        if (sj > tg) v = -3.0e38f;
        P[j][rr] = v;
        vmax = fmaxf(vmax, v);
      }
      for (int off = 1; off < 16; off <<= 1) vmax = fmaxf(vmax, __shfl_xor(vmax, off));
      const float mnew = fmaxf(mrow[rr], vmax);
      const float alpha = __expf(mrow[rr] - mnew);
      mrow[rr] = mnew;
      lrow[rr] *= alpha;
#pragma unroll
      for (int ht = 0; ht < 8; ++ht) O[ht][rr] *= alpha;
      float rsum = 0.f;
#pragma unroll
      for (int j = 0; j < 4; ++j) {
        float e = __expf(P[j][rr] - mnew);
        P[j][rr] = e;
        rsum += e;
      }
      for (int off = 1; off < 16; off <<= 1) rsum += __shfl_xor(rsum, off);
      lrow[rr] += rsum;
    }

    // P: C-layout regs -> LDS [t][s] (A-layout source). Own wave rows only.
#pragma unroll
    for (int rr = 0; rr < 4; ++rr)
#pragma unroll
      for (int j = 0; j < 4; ++j)
        Ps[(w * 16 + q * 4 + rr) * 64 + j * 16 + ml] = f2bf(P[j][rr]);

    // O += P V   (acc over s = 2 ksteps)
#pragma unroll
    for (int ks = 0; ks < 2; ++ks) {
      short8 ap = *(const short8*)&Ps[(w * 16 + ml) * 64 + ks * 32 + q * 8];
#pragma unroll
      for (int ht = 0; ht < 8; ++ht) {
        short8 bv = *(const short8*)&Vts[(ht * 16 + ml) * 64 + ks * 32 + q * 8];
        O[ht] = __builtin_amdgcn_mfma_f32_16x16x32_bf16(ap, bv, O[ht], 0, 0, 0);
      }
    }
    __syncthreads();
  }

  // epilogue: normalize, gate, store bf16 (M, N*H)
#pragma unroll
  for (int rr = 0; rr < 4; ++rr) {
    const int tg = t0 + w * 16 + q * 4 + rr;
    const size_t ob = ((size_t)(b * 1024 + tg) * 32 + n) * 128;
    const float inv = 1.0f / lrow[rr];
#pragma unroll
    for (int ht = 0; ht < 8; ++ht) {
      const int h = ht * 16 + ml;
      attn_out[ob + h] = f2bf(O[ht][rr] * inv * bf2f(sgate[ob + h]));
    }
  }
}

// ---------------------------------------------------------------------------
extern "C" void kernel_launch(void* const* d_in, const int* in_sizes, int n_in,
                              void* d_out, int out_size, void* d_ws, size_t ws_size,
                              hipStream_t stream) {
  (void)in_sizes; (void)n_in; (void)out_size; (void)ws_size;
  const float* x = (const float*)d_in[0];
  const int* pos = (const int*)d_in[1];
  const float* wq = (const float*)d_in[2];
  const float* wk = (const float*)d_in[3];
  const float* wv = (const float*)d_in[4];
  const float* wo = (const float*)d_in[5];
  const float* qnw = (const float*)d_in[6];
  const float* knw = (const float*)d_in[7];
  float* out = (float*)d_out;

  // workspace layout (ushort elements); total ~304 MiB
  unsigned short* ws = (unsigned short*)d_ws;
  unsigned short* x_bf = ws;                         // 16777216
  unsigned short* wT = x_bf + 16777216;              // 41943040 (wq^T|wk^T|wv^T)
  unsigned short* woT = wT + 41943040;               // 16777216
  unsigned short* qkv = woT + 16777216;              // 41943040
  unsigned short* q_rot = qkv + 41943040;            // 16777216
  unsigned short* sgb = q_rot + 16777216;            // 16777216
  unsigned short* k_rot = sgb + 16777216;            // 4194304
  unsigned short* vtb = k_rot + 4194304;             // 4194304
  unsigned short* attn = wT;  // wT dead after GEMM1; reuse for attention out

  dim3 tb(32, 8);
  transpose_cvt<<<dim3(256, 128), tb, 0, stream>>>(wq, wT, 4096, 8192);
  transpose_cvt<<<dim3(32, 128), tb, 0, stream>>>(wk, wT + (size_t)8192 * 4096, 4096, 1024);
  transpose_cvt<<<dim3(32, 128), tb, 0, stream>>>(wv, wT + (size_t)9216 * 4096, 4096, 1024);
  transpose_cvt<<<dim3(128, 128), tb, 0, stream>>>(wo, woT, 4096, 4096);
  cvt_f32_bf16<<<16384, 256, 0, stream>>>(x, x_bf, 4194304);

  gemm_bt<true><<<dim3(80, 32), 256, 0, stream>>>(x_bf, wT, (void*)qkv, 4096, 10240, 4096);
  postproc_kernel<<<49152, 256, 0, stream>>>(qkv, pos, qnw, knw, q_rot, sgb, k_rot, vtb);
  attn_kernel<<<2048, 256, 0, stream>>>(q_rot, k_rot, vtb, sgb, attn);
  gemm_bt<false><<<dim3(32, 32), 256, 0, stream>>>(attn, woT, (void*)out, 4096, 4096, 4096);
}

// Round 2
// 1129.546 us; speedup vs baseline: 1.2065x; 1.2065x over previous
//
#include <hip/hip_runtime.h>
#include <cstdint>
#include <cstddef>

// ---------------------------------------------------------------------------
// Fused GQA attention block for MI355X (gfx950).
// B=4 T=1024 D=4096 N=32 Kh=8 G=4 H=128, rotary=80, theta=1e6, eps=1e-6.
// Pipeline: [transpose+cvt weights/x -> bf16] -> GEMM(qkv) -> norm/rope/gate
//           + V transpose -> flash attention (causal) -> GEMM(out proj).
// R1 change: XOR-swizzled LDS layouts (chunk' = chunk ^ (row & mask)) to kill
// the 8-way ds_read_b128 bank conflicts (1.26e8 conflict cycles in R0 GEMM1),
// while keeping global_load_lds's lane-contiguous LDS-dest constraint.
// MFMA layouts (guide-verified, 16x16x32 bf16):
//   A-frag: A[m=lane&15][k=(lane>>4)*8+j]
//   B-frag: B[k=(lane>>4)*8+j][n=lane&15]  (from B^T rows)
//   C/D   : row=(lane>>4)*4+r, col=lane&15
// ---------------------------------------------------------------------------

typedef __attribute__((ext_vector_type(8))) short short8;
typedef __attribute__((ext_vector_type(4))) float float4v;

__device__ __forceinline__ unsigned short f2bf(float f) {
  unsigned u = __builtin_bit_cast(unsigned, f);
  u += 0x7fffu + ((u >> 16) & 1u);            // RNE
  return (unsigned short)(u >> 16);
}
__device__ __forceinline__ float bf2f(unsigned short h) {
  unsigned u = ((unsigned)h) << 16;
  return __builtin_bit_cast(float, u);
}

// async global->LDS, 16B per lane. LDS dest is wave-uniform base + lane*16.
__device__ __forceinline__ void gload_lds16(const void* g, void* l) {
  typedef const __attribute__((address_space(1))) void as1_cv;
  typedef __attribute__((address_space(3))) void as3_v;
  __builtin_amdgcn_global_load_lds((as1_cv*)g, (as3_v*)l, 16, 0, 0);
}

// ---------------------------------------------------------------------------
// Transpose + f32->bf16 convert: dst[c][r] = bf16(src[r][c]); src is (R, C).
// ---------------------------------------------------------------------------
__global__ __launch_bounds__(256) void transpose_cvt(
    const float* __restrict__ src, unsigned short* __restrict__ dst,
    int R, int C) {
  __shared__ float tile[32][33];
  const int c0 = blockIdx.x * 32, r0 = blockIdx.y * 32;
  for (int i = threadIdx.y; i < 32; i += 8)
    tile[i][threadIdx.x] = src[(size_t)(r0 + i) * C + c0 + threadIdx.x];
  __syncthreads();
  for (int i = threadIdx.y; i < 32; i += 8)
    dst[(size_t)(c0 + i) * R + r0 + threadIdx.x] = f2bf(tile[threadIdx.x][i]);
}

__global__ __launch_bounds__(256) void cvt_f32_bf16(
    const float* __restrict__ src, unsigned short* __restrict__ dst, int n4) {
  int i = blockIdx.x * blockDim.x + threadIdx.x;
  if (i >= n4) return;
  float4 f = ((const float4*)src)[i];
  ushort4 o;
  o.x = f2bf(f.x); o.y = f2bf(f.y); o.z = f2bf(f.z); o.w = f2bf(f.w);
  ((ushort4*)dst)[i] = o;
}

// bf16 64x64-tile transpose for V: qkv cols [9216+kh*128, +128) -> vt (b,kh,h,t).
// grid (16 t-tiles, 2 h-tiles, 32 b*kh), block 256.
__global__ __launch_bounds__(256) void v_transpose(
    const unsigned short* __restrict__ qkv, unsigned short* __restrict__ vtb) {
  __shared__ unsigned short tile[64][65];
  const int t0 = blockIdx.x * 64, h0 = blockIdx.y * 64;
  const int bk = blockIdx.z, b = bk >> 3, kh = bk & 7;
  const int tx = threadIdx.x & 63, ty = threadIdx.x >> 6;
  const unsigned short* src =
      qkv + (size_t)(b * 1024 + t0) * 10240 + 9216 + kh * 128 + h0;
  for (int i = ty; i < 64; i += 4)
    tile[i][tx] = src[(size_t)i * 10240 + tx];
  __syncthreads();
  unsigned short* dst = vtb + ((size_t)bk * 128 + h0) * 1024 + t0;
  for (int i = ty; i < 64; i += 4)
    dst[(size_t)i * 1024 + tx] = tile[tx][i];
}

// ---------------------------------------------------------------------------
// GEMM: C(M,N) = A(M,Kd) * BT(N,Kd)^T, bf16 in, f32 acc. 128x128 tile, BK=64.
// LDS chunk swizzle: position (row, c) holds global chunk c ^ (row & 7).
// ---------------------------------------------------------------------------
template <bool BF16OUT>
__global__ __launch_bounds__(256) void gemm_bt(
    const unsigned short* __restrict__ A, const unsigned short* __restrict__ BT,
    void* __restrict__ Cv, int M, int N, int Kd) {
  constexpr int BK = 64;
  __shared__ unsigned short As[128 * BK];
  __shared__ unsigned short Bs[128 * BK];

  const int tid = threadIdx.x;
  const int lane = tid & 63;
  const int wv = tid >> 6;
  const int wr = wv >> 1, wc = wv & 1;
  const int m0 = blockIdx.y * 128, n0 = blockIdx.x * 128;
  const int ml = lane & 15, q = lane >> 4;

  // staging: LDS pos (row=tid>>3 (+32*it), chunk=tid&7); fetch global chunk^row
  const int r0 = tid >> 3;
  const int cSw = ((tid & 7) ^ (r0 & 7)) * 8;        // swizzled global col (ushorts)
  const unsigned short* gA = A + (size_t)(m0 + r0) * Kd + cSw;
  const unsigned short* gB = BT + (size_t)(n0 + r0) * Kd + cSw;
  unsigned short* lA = &As[r0 * BK + (tid & 7) * 8];
  unsigned short* lB = &Bs[r0 * BK + (tid & 7) * 8];

  float4v acc[4][4];
#pragma unroll
  for (int i = 0; i < 4; ++i)
#pragma unroll
    for (int j = 0; j < 4; ++j) acc[i][j] = (float4v)0.0f;

  for (int k0 = 0; k0 < Kd; k0 += BK) {
#pragma unroll
    for (int it = 0; it < 4; ++it) {
      gload_lds16(gA + (size_t)it * 32 * Kd + k0, lA + it * 32 * BK);
      gload_lds16(gB + (size_t)it * 32 * Kd + k0, lB + it * 32 * BK);
    }
    __syncthreads();
#pragma unroll
    for (int ks = 0; ks < 2; ++ks) {
      short8 af[4], bfr[4];
      const int csw = ((ks * 4 + q) ^ (ml & 7)) * 8;  // swizzled chunk for reads
#pragma unroll
      for (int i = 0; i < 4; ++i)
        af[i] = *(const short8*)&As[(wr * 64 + i * 16 + ml) * BK + csw];
#pragma unroll
      for (int j = 0; j < 4; ++j)
        bfr[j] = *(const short8*)&Bs[(wc * 64 + j * 16 + ml) * BK + csw];
#pragma unroll
      for (int i = 0; i < 4; ++i)
#pragma unroll
        for (int j = 0; j < 4; ++j)
          acc[i][j] = __builtin_amdgcn_mfma_f32_16x16x32_bf16(af[i], bfr[j], acc[i][j], 0, 0, 0);
    }
    __syncthreads();
  }

#pragma unroll
  for (int i = 0; i < 4; ++i) {
#pragma unroll
    for (int j = 0; j < 4; ++j) {
      const int grow = m0 + wr * 64 + i * 16 + q * 4;
      const int gcol = n0 + wc * 64 + j * 16 + ml;
#pragma unroll
      for (int r = 0; r < 4; ++r) {
        size_t idx = (size_t)(grow + r) * N + gcol;
        if constexpr (BF16OUT)
          ((unsigned short*)Cv)[idx] = f2bf(acc[i][j][r]);
        else
          ((float*)Cv)[idx] = acc[i][j][r];
      }
    }
  }
}

// ---------------------------------------------------------------------------
// Postprocess q/gate/k (V handled by v_transpose):
//   hs<32 : q head hs  -> rmsnorm, rope -> q_rot; gate -> sigmoid -> sgb
//   hs>=32: k head     -> rmsnorm, rope -> k_rot  (layout (b,kh,t,h))
// One wave per (row m, slot hs in 0..39). grid 40960, block 256.
// ---------------------------------------------------------------------------
__global__ __launch_bounds__(256) void postproc_kernel(
    const unsigned short* __restrict__ qkv, const int* __restrict__ positions,
    const float* __restrict__ qnw, const float* __restrict__ knw,
    unsigned short* __restrict__ q_rot, unsigned short* __restrict__ sgb,
    unsigned short* __restrict__ k_rot) {
  const int wave = threadIdx.x >> 6, lane = threadIdx.x & 63;
  const int gslot = blockIdx.x * 4 + wave;
  const int m = gslot / 40, hs = gslot % 40;
  const int b = m >> 10, t = m & 1023;

  const unsigned short* base = (hs < 32)
      ? qkv + (size_t)m * 10240 + hs * 256
      : qkv + (size_t)m * 10240 + 8192 + (hs - 32) * 128;

  float v1 = bf2f(base[lane]);        // h = lane
  float v2 = bf2f(base[64 + lane]);   // h = lane + 64

  // RMS norm over 128 (1+w applied before rope; rope mixes channels)
  float ss = v1 * v1 + v2 * v2;
  for (int off = 32; off > 0; off >>= 1) ss += __shfl_xor(ss, off);
  const float r = rsqrtf(ss * (1.0f / 128.0f) + 1e-6f);
  const float* nw = (hs < 32) ? qnw : knw;
  v1 *= r * (1.0f + nw[lane]);
  v2 *= r * (1.0f + nw[64 + lane]);

  // RoPE dims 0..79: pair (i, i+40). ln(1e6)/40 = 0.34538776...
  const float pos = (float)positions[m];
  const int i1 = (lane < 40) ? lane : lane - 40;
  const float ang1 = pos * expf(-0.3453877639491068f * (float)i1);
  const float s1 = sinf(ang1), c1 = cosf(ang1);
  const float ang2 = pos * expf(-0.3453877639491068f * (float)(lane + 24));
  const float s2 = sinf(ang2), c2 = cosf(ang2);

  const float shA1 = __shfl(v1, (lane + 40) & 63);
  const float shA2 = __shfl(v2, (lane + 40) & 63);
  const float shX = __shfl(v1, (lane + 24) & 63);
  const float pA = (lane < 24) ? shA1 : shA2;  // x[lane+40]
  const float o1 = (lane < 40) ? (v1 * c1 - pA * s1) : (v1 * c1 + shX * s1);
  const float o2 = (lane < 16) ? (v2 * c2 + shX * s2) : v2;

  if (hs < 32) {
    size_t qb = ((size_t)m * 32 + hs) * 128;
    q_rot[qb + lane] = f2bf(o1);
    q_rot[qb + 64 + lane] = f2bf(o2);
    float g1 = bf2f(base[128 + lane]), g2 = bf2f(base[192 + lane]);
    sgb[qb + lane] = f2bf(1.0f / (1.0f + expf(-g1)));
    sgb[qb + 64 + lane] = f2bf(1.0f / (1.0f + expf(-g2)));
  } else {
    const int kh = hs - 32;
    size_t kb = ((size_t)(b * 8 + kh) * 1024 + t) * 128;
    k_rot[kb + lane] = f2bf(o1);
    k_rot[kb + 64 + lane] = f2bf(o2);
  }
}

// ---------------------------------------------------------------------------
// Flash attention. Block = (b, n, 64-row Q tile). 4 waves x 16 q-rows.
// Ks/Vts XOR-swizzled; Ps padded to stride 72. LDS = 16K+16K+9K = 41KB.
// ---------------------------------------------------------------------------
__global__ __launch_bounds__(256) void attn_kernel(
    const unsigned short* __restrict__ q_rot, const unsigned short* __restrict__ k_rot,
    const unsigned short* __restrict__ vt, const unsigned short* __restrict__ sgate,
    unsigned short* __restrict__ attn_out) {
  __shared__ unsigned short Ks[64 * 128];   // 16 chunks/row, swizzle mask 15
  __shared__ unsigned short Vts[128 * 64];  // 8 chunks/row, swizzle mask 7
  __shared__ unsigned short Ps[64 * 72];    // padded, plain stores

  const int tid = threadIdx.x;
  const int lane = tid & 63, w = tid >> 6;
  const int qt = blockIdx.x & 15;
  const int n = (blockIdx.x >> 4) & 31;
  const int b = blockIdx.x >> 9;
  const int kh = n >> 2;
  const int t0 = qt * 64;
  const int ml = lane & 15, q = lane >> 4;
  const float SCALE = 0.08838834764831845f;  // H^-0.5

  short8 aq[4];
  {
    const unsigned short* qp =
        q_rot + (((size_t)(b * 1024 + t0 + w * 16 + ml)) * 32 + n) * 128 + q * 8;
#pragma unroll
    for (int ks = 0; ks < 4; ++ks) aq[ks] = *(const short8*)(qp + ks * 32);
  }

  float4v O[8];
#pragma unroll
  for (int i = 0; i < 8; ++i) O[i] = (float4v)0.0f;
  float mrow[4] = {-3e38f, -3e38f, -3e38f, -3e38f};
  float lrow[4] = {0.f, 0.f, 0.f, 0.f};

  const unsigned short* kbase = k_rot + (size_t)(b * 8 + kh) * 1024 * 128;
  const unsigned short* vbase = vt + (size_t)(b * 8 + kh) * 128 * 1024;
  const int rK = tid >> 4, cK = tid & 15;  // K stage: 64 rows x 16 chunks
  const int cKsw = (cK ^ rK) * 8;          // rK&15 == rK
  const int rV = tid >> 3, cV = tid & 7;   // V stage: 128 rows x 8 chunks
  const int cVsw = (cV ^ (rV & 7)) * 8;

  for (int si = 0; si <= qt; ++si) {
    const int s0 = si * 64;
#pragma unroll
    for (int it = 0; it < 4; ++it) {
      const int li = it * 256 + tid;
      gload_lds16(kbase + (size_t)(s0 + rK + it * 16) * 128 + cKsw, &Ks[li * 8]);
      gload_lds16(vbase + (size_t)(rV + it * 32) * 1024 + s0 + cVsw, &Vts[li * 8]);
    }
    __syncthreads();

    // S = Q K^T
    float4v Sv[4];
#pragma unroll
    for (int j = 0; j < 4; ++j) Sv[j] = (float4v)0.0f;
#pragma unroll
    for (int ks = 0; ks < 4; ++ks) {
#pragma unroll
      for (int j = 0; j < 4; ++j) {
        short8 bk = *(const short8*)&Ks[(j * 16 + ml) * 128 + (((ks * 4 + q) ^ ml) * 8)];
        Sv[j] = __builtin_amdgcn_mfma_f32_16x16x32_bf16(aq[ks], bk, Sv[j], 0, 0, 0);
      }
    }

    // scale + causal mask + online softmax (rows: t = t0+w*16+q*4+rr)
    float P[4][4];
#pragma unroll
    for (int rr = 0; rr < 4; ++rr) {
      const int tg = t0 + w * 16 + q * 4 + rr;
      float vmax = -3e38f;
#pragma unroll
      for (int j = 0; j < 4; ++j) {
        const int sj = s0 + j * 16 + ml;
        float v = Sv[j][rr] * SCALE;
        if (sj > tg) v = -3.0e38f;
        P[j][rr] = v;
        vmax = fmaxf(vmax, v);
      }
      for (int off = 1; off < 16; off <<= 1) vmax = fmaxf(vmax, __shfl_xor(vmax, off));
      const float mnew = fmaxf(mrow[rr], vmax);
      const float alpha = __expf(mrow[rr] - mnew);
      mrow[rr] = mnew;
      lrow[rr] *= alpha;
#pragma unroll
      for (int ht = 0; ht < 8; ++ht) O[ht][rr] *= alpha;
      float rsum = 0.f;
#pragma unroll
      for (int j = 0; j < 4; ++j) {
        float e = __expf(P[j][rr] - mnew);
        P[j][rr] = e;
        rsum += e;
      }
      for (int off = 1; off < 16; off <<= 1) rsum += __shfl_xor(rsum, off);
      lrow[rr] += rsum;
    }

    // P: C-layout regs -> LDS [t][s] (padded stride 72)
#pragma unroll
    for (int rr = 0; rr < 4; ++rr)
#pragma unroll
      for (int j = 0; j < 4; ++j)
        Ps[(w * 16 + q * 4 + rr) * 72 + j * 16 + ml] = f2bf(P[j][rr]);

    // O += P V
#pragma unroll
    for (int ks = 0; ks < 2; ++ks) {
      short8 ap = *(const short8*)&Ps[(w * 16 + ml) * 72 + ks * 32 + q * 8];
#pragma unroll
      for (int ht = 0; ht < 8; ++ht) {
        short8 bv = *(const short8*)&Vts[(ht * 16 + ml) * 64 + (((ks * 4 + q) ^ (ml & 7)) * 8)];
        O[ht] = __builtin_amdgcn_mfma_f32_16x16x32_bf16(ap, bv, O[ht], 0, 0, 0);
      }
    }
    __syncthreads();
  }

  // epilogue: normalize, gate, store bf16 (M, N*H)
#pragma unroll
  for (int rr = 0; rr < 4; ++rr) {
    const int tg = t0 + w * 16 + q * 4 + rr;
    const size_t ob = ((size_t)(b * 1024 + tg) * 32 + n) * 128;
    const float inv = 1.0f / lrow[rr];
#pragma unroll
    for (int ht = 0; ht < 8; ++ht) {
      const int h = ht * 16 + ml;
      attn_out[ob + h] = f2bf(O[ht][rr] * inv * bf2f(sgate[ob + h]));
    }
  }
}

// ---------------------------------------------------------------------------
extern "C" void kernel_launch(void* const* d_in, const int* in_sizes, int n_in,
                              void* d_out, int out_size, void* d_ws, size_t ws_size,
                              hipStream_t stream) {
  (void)in_sizes; (void)n_in; (void)out_size; (void)ws_size;
  const float* x = (const float*)d_in[0];
  const int* pos = (const int*)d_in[1];
  const float* wq = (const float*)d_in[2];
  const float* wk = (const float*)d_in[3];
  const float* wv = (const float*)d_in[4];
  const float* wo = (const float*)d_in[5];
  const float* qnw = (const float*)d_in[6];
  const float* knw = (const float*)d_in[7];
  float* out = (float*)d_out;

  unsigned short* ws = (unsigned short*)d_ws;
  unsigned short* x_bf = ws;                         // 16777216
  unsigned short* wT = x_bf + 16777216;              // 41943040 (wq^T|wk^T|wv^T)
  unsigned short* woT = wT + 41943040;               // 16777216
  unsigned short* qkv = woT + 16777216;              // 41943040
  unsigned short* q_rot = qkv + 41943040;            // 16777216
  unsigned short* sgb = q_rot + 16777216;            // 16777216
  unsigned short* k_rot = sgb + 16777216;            // 4194304
  unsigned short* vtb = k_rot + 4194304;             // 4194304
  unsigned short* attn = wT;  // wT dead after GEMM1; reuse for attention out

  dim3 tb(32, 8);
  transpose_cvt<<<dim3(256, 128), tb, 0, stream>>>(wq, wT, 4096, 8192);
  transpose_cvt<<<dim3(32, 128), tb, 0, stream>>>(wk, wT + (size_t)8192 * 4096, 4096, 1024);
  transpose_cvt<<<dim3(32, 128), tb, 0, stream>>>(wv, wT + (size_t)9216 * 4096, 4096, 1024);
  transpose_cvt<<<dim3(128, 128), tb, 0, stream>>>(wo, woT, 4096, 4096);
  cvt_f32_bf16<<<16384, 256, 0, stream>>>(x, x_bf, 4194304);

  gemm_bt<true><<<dim3(80, 32), 256, 0, stream>>>(x_bf, wT, (void*)qkv, 4096, 10240, 4096);
  postproc_kernel<<<40960, 256, 0, stream>>>(qkv, pos, qnw, knw, q_rot, sgb, k_rot);
  v_transpose<<<dim3(16, 2, 32), 256, 0, stream>>>(qkv, vtb);
  attn_kernel<<<2048, 256, 0, stream>>>(q_rot, k_rot, vtb, sgb, attn);
  gemm_bt<false><<<dim3(32, 32), 256, 0, stream>>>(attn, woT, (void*)out, 4096, 4096, 4096);
}